// Round 10
// baseline (1678.252 us; speedup 1.0000x reference)
//
#include <hip/hip_runtime.h>
#include <hip/hip_cooperative_groups.h>
#include <math.h>

namespace cg = cooperative_groups;

#define LEVELS 16
#define HASHMAP_SIZE (1 << 19)
#define N_POINTS 2097152
#define CHUNKPTS (N_POINTS / 4)   // 524288
#define NCHUNK 4
#define COOP_BLOCKS 1024
#define GATHER_BLOCKS 512

typedef __attribute__((ext_vector_type(8))) short bf16x8;
typedef __attribute__((ext_vector_type(4))) float f32x4;
typedef __attribute__((ext_vector_type(4))) unsigned u32x4;

__device__ __constant__ float c_res[LEVELS] = {
    16.f, 24.f, 36.f, 54.f, 81.f, 121.f, 182.f, 273.f,
    410.f, 615.f, 922.f, 1383.f, 2075.f, 3113.f, 4670.f, 7006.f};

__device__ __forceinline__ unsigned short f2bf(float f) {
    unsigned u = __builtin_bit_cast(unsigned, f);
    u += 0x7FFFu + ((u >> 16) & 1u);   // RNE
    return (unsigned short)(u >> 16);
}
__device__ __forceinline__ unsigned cvt_pk_bf16(float a, float b) {
    unsigned r;
    asm("v_cvt_pk_bf16_f32 %0, %1, %2" : "=v"(r) : "v"(a), "v"(b));
    return r;
}

// LDS byte-swizzle (T2/G4)
__device__ __forceinline__ unsigned swz(unsigned row, unsigned colbyte) {
    return row * 128u + (colbyte ^ ((row & 7u) << 4));
}

__device__ __forceinline__ unsigned hash3(float px, float py, float pz, float r) {
    const int ix = (int)floorf(px * r);
    const int iy = (int)floorf(py * r);
    const int iz = (int)floorf(pz * r);
    const unsigned h = (unsigned)ix * 73856093u
                     ^ (unsigned)iy * 19349663u
                     ^ (unsigned)iz * 83492791u;
    return h & (unsigned)(HASHMAP_SIZE - 1);
}

__device__ __forceinline__ bf16x8 load_wfrag(const float* __restrict__ W, int ncols,
                                             int n, int k0, int kmax) {
    bf16x8 r;
    #pragma unroll
    for (int j = 0; j < 8; ++j) {
        const int k = k0 + j;
        const float v = (k < kmax) ? W[k * ncols + n] : 0.f;
        r[j] = (short)f2bf(v);
    }
    return r;
}

// ===================== gather: 4 pts/thread-iter, XCD-pinned pair =====================
__device__ __forceinline__ void gather_chunk(
    const float* __restrict__ x, const unsigned* __restrict__ tabp,
    unsigned* __restrict__ featbuf, int chunkbase, int chunkpts,
    int pair, int bip, int nbp)
{
    const int l0 = pair, l1 = pair + 8;
    const float r0 = c_res[l0], r1 = c_res[l1];
    const int tid = threadIdx.x;
    const int groups = chunkpts >> 2;
    const int gstride = nbp * 256;
    const unsigned* __restrict__ t0 = tabp + (size_t)l0 * HASHMAP_SIZE;
    const unsigned* __restrict__ t1 = tabp + (size_t)l1 * HASHMAP_SIZE;
    for (int g = bip * 256 + tid; g < groups; g += gstride) {
        const int pl = g * 4;
        const size_t pg = (size_t)chunkbase + pl;
        const float4 xa = *(const float4*)(x + pg * 3 + 0);
        const float4 xb = *(const float4*)(x + pg * 3 + 4);
        const float4 xc = *(const float4*)(x + pg * 3 + 8);
        const unsigned iA0 = hash3(xa.x, xa.y, xa.z, r0), iB0 = hash3(xa.x, xa.y, xa.z, r1);
        const unsigned iA1 = hash3(xa.w, xb.x, xb.y, r0), iB1 = hash3(xa.w, xb.x, xb.y, r1);
        const unsigned iA2 = hash3(xb.z, xb.w, xc.x, r0), iB2 = hash3(xb.z, xb.w, xc.x, r1);
        const unsigned iA3 = hash3(xc.y, xc.z, xc.w, r0), iB3 = hash3(xc.y, xc.z, xc.w, r1);
        u32x4 gA, gB;
        gA.x = t0[iA0]; gA.y = t0[iA1]; gA.z = t0[iA2]; gA.w = t0[iA3];
        gB.x = t1[iB0]; gB.y = t1[iB1]; gB.z = t1[iB2]; gB.w = t1[iB3];
        __builtin_nontemporal_store(gA, (u32x4*)(featbuf + (size_t)l0 * chunkpts + pl));
        __builtin_nontemporal_store(gB, (u32x4*)(featbuf + (size_t)l1 * chunkpts + pl));
    }
}

// ===================== MLP: one 256-pt tile, all three layers on MFMA ===============
__device__ __forceinline__ void mlp_tile(
    const unsigned* __restrict__ feat, const float* __restrict__ view_dir,
    const unsigned short* __restrict__ w0p, const unsigned short* __restrict__ w1p,
    const float* __restrict__ b0, const float* __restrict__ b1,
    const float* __restrict__ W2, const float* __restrict__ b2,
    float* __restrict__ out, char* __restrict__ actsb,
    int chunkbase, int chunkpts, int tile)
{
    const int tid = threadIdx.x;
    const int gl = tile * 256 + tid;
    const size_t gid = (size_t)chunkbase + gl;

    unsigned fw[18];
    #pragma unroll
    for (int l = 0; l < LEVELS; ++l)
        fw[l] = feat[(size_t)l * chunkpts + gl];
    fw[16] = (unsigned)f2bf(view_dir[gid * 3 + 0])
           | ((unsigned)f2bf(view_dir[gid * 3 + 1]) << 16);
    fw[17] = (unsigned)f2bf(view_dir[gid * 3 + 2]);

    {
        const unsigned row = (unsigned)tid;
        #pragma unroll
        for (int c = 0; c < 8; ++c) {
            int4 v;
            if (c < 4)       v = make_int4((int)fw[4*c], (int)fw[4*c+1], (int)fw[4*c+2], (int)fw[4*c+3]);
            else if (c == 4) v = make_int4((int)fw[16], (int)fw[17], 0, 0);
            else             v = make_int4(0, 0, 0, 0);
            *(int4*)(actsb + swz(row, (unsigned)(c * 16))) = v;
        }
    }
    // No barriers: wave w touches only rows [64w, 64w+64).

    const int lane = tid & 63;
    const int lr = lane & 15;
    const int lg = lane >> 4;
    const unsigned Rbase = (unsigned)(tid & ~63);

    #pragma unroll
    for (int layer = 0; layer < 2; ++layer) {
        const unsigned short* const Wp = layer ? w1p : w0p;
        const float* const bg = layer ? b1 : b0;

        bf16x8 bw[8];
        #pragma unroll
        for (int nt = 0; nt < 4; ++nt)
            #pragma unroll
            for (int ks = 0; ks < 2; ++ks)
                bw[nt * 2 + ks] = *(const bf16x8*)(Wp + (nt * 16 + lr) * 64 + (ks * 32 + lg * 8));

        #pragma unroll
        for (int rt = 0; rt < 4; ++rt) {
            bf16x8 aa[2];
            #pragma unroll
            for (int ks = 0; ks < 2; ++ks) {
                const unsigned row = Rbase + (unsigned)(rt * 16 + lr);
                aa[ks] = *(const bf16x8*)(actsb + swz(row, (unsigned)((ks * 4 + lg) * 16)));
            }
            #pragma unroll
            for (int nt = 0; nt < 4; ++nt) {
                const float bv = bg[nt * 16 + lr];
                f32x4 c = {bv, bv, bv, bv};
                c = __builtin_amdgcn_mfma_f32_16x16x32_bf16(aa[0], bw[nt * 2 + 0], c, 0, 0, 0);
                c = __builtin_amdgcn_mfma_f32_16x16x32_bf16(aa[1], bw[nt * 2 + 1], c, 0, 0, 0);
                const unsigned u01 = cvt_pk_bf16(fmaxf(c[0], 0.f), fmaxf(c[1], 0.f));
                const unsigned u23 = cvt_pk_bf16(fmaxf(c[2], 0.f), fmaxf(c[3], 0.f));
                const unsigned col = (unsigned)(nt * 16 + lr);
                const unsigned rbase = Rbase + (unsigned)(rt * 16 + lg * 4);
                *(unsigned short*)(actsb + swz(rbase + 0, col * 2)) = (unsigned short)u01;
                *(unsigned short*)(actsb + swz(rbase + 1, col * 2)) = (unsigned short)(u01 >> 16);
                *(unsigned short*)(actsb + swz(rbase + 2, col * 2)) = (unsigned short)u23;
                *(unsigned short*)(actsb + swz(rbase + 3, col * 2)) = (unsigned short)(u23 >> 16);
            }
        }
    }

    // Layer 2 (64->4) on MFMA; bounce via wave-own LDS rows for coalesced stores
    {
        const bool valid = (lr < 4);
        bf16x8 bw2[2];
        #pragma unroll
        for (int ks = 0; ks < 2; ++ks) {
            if (valid) bw2[ks] = load_wfrag(W2, 4, lr, ks * 32 + lg * 8, 64);
            else       bw2[ks] = bf16x8{0,0,0,0,0,0,0,0};
        }
        const float bc = valid ? b2[lr] : 0.f;

        #pragma unroll
        for (int rt = 0; rt < 4; ++rt) {
            bf16x8 aa[2];
            #pragma unroll
            for (int ks = 0; ks < 2; ++ks) {
                const unsigned row = Rbase + (unsigned)(rt * 16 + lr);
                aa[ks] = *(const bf16x8*)(actsb + swz(row, (unsigned)((ks * 4 + lg) * 16)));
            }
            f32x4 c = {bc, bc, bc, bc};
            c = __builtin_amdgcn_mfma_f32_16x16x32_bf16(aa[0], bw2[0], c, 0, 0, 0);
            c = __builtin_amdgcn_mfma_f32_16x16x32_bf16(aa[1], bw2[1], c, 0, 0, 0);
            if (valid) {
                #pragma unroll
                for (int r = 0; r < 4; ++r) {
                    const unsigned row = Rbase + (unsigned)(rt * 16 + lg * 4 + r);
                    *(float*)(actsb + row * 128u + ((row & 7u) << 4) + (unsigned)lr * 4u) = c[r];
                }
            }
        }
        const unsigned row = (unsigned)tid;
        const f32x4 o = *(const f32x4*)(actsb + row * 128u + ((row & 7u) << 4));
        out[gid * 3 + 0] = 1.f / (1.f + __expf(-o[0]));
        out[gid * 3 + 1] = 1.f / (1.f + __expf(-o[1]));
        out[gid * 3 + 2] = 1.f / (1.f + __expf(-o[2]));
        out[(size_t)N_POINTS * 3 + gid] = fmaxf(o[3], 0.f);
    }
}

// ===================== Pass A0: tables f32 -> packed bf16x2 (+ weights) ==============
__global__ __launch_bounds__(256) void conv_tables(const float* __restrict__ tables,
                                                   unsigned* __restrict__ tabp,
                                                   const float* __restrict__ W0,
                                                   const float* __restrict__ W1,
                                                   unsigned short* __restrict__ w0p,
                                                   unsigned short* __restrict__ w1p) {
    const int t = blockIdx.x * 256 + threadIdx.x;
    if (blockIdx.x < 16) {
        const int i = t;
        const int n = i >> 6, k = i & 63;
        w0p[n * 64 + k] = f2bf((k < 35) ? W0[k * 64 + n] : 0.f);
        w1p[n * 64 + k] = f2bf(W1[k * 64 + n]);
    }
    const float4 a = *reinterpret_cast<const float4*>(tables + (size_t)t * 8);
    const float4 b = *reinterpret_cast<const float4*>(tables + (size_t)t * 8 + 4);
    uint4 o;
    o.x = (unsigned)f2bf(a.x) | ((unsigned)f2bf(a.y) << 16);
    o.y = (unsigned)f2bf(a.z) | ((unsigned)f2bf(a.w) << 16);
    o.z = (unsigned)f2bf(b.x) | ((unsigned)f2bf(b.y) << 16);
    o.w = (unsigned)f2bf(b.z) | ((unsigned)f2bf(b.w) << 16);
    *reinterpret_cast<uint4*>(tabp + (size_t)t * 4) = o;
}

// ===================== Cooperative producer-consumer pipeline =======================
__global__ __launch_bounds__(256, 4) void nerf_coop(
    const float* __restrict__ x, const float* __restrict__ view_dir,
    const unsigned* __restrict__ tabp,
    const unsigned short* __restrict__ w0p, const unsigned short* __restrict__ w1p,
    const float* __restrict__ b0, const float* __restrict__ b1,
    const float* __restrict__ W2, const float* __restrict__ b2,
    float* __restrict__ out, unsigned* __restrict__ featbase)
{
    __shared__ __align__(16) unsigned short acts[256 * 64];   // 32 KB
    char* const actsb = (char*)acts;
    cg::grid_group grid = cg::this_grid();
    const int bid = blockIdx.x;
    unsigned* const feat0 = featbase;
    unsigned* const feat1 = featbase + (size_t)CHUNKPTS * LEVELS;

    // prologue: ALL blocks gather chunk 0 -> feat0
    gather_chunk(x, tabp, feat0, 0, CHUNKPTS, bid & 7, bid >> 3, COOP_BLOCKS / 8);
    __threadfence();
    grid.sync();

    for (int s = 0; s < NCHUNK - 1; ++s) {     // s = 0,1,2
        unsigned* const fcur = (s & 1) ? feat1 : feat0;
        unsigned* const fnxt = (s & 1) ? feat0 : feat1;
        if (bid < GATHER_BLOCKS) {
            gather_chunk(x, tabp, fnxt, (s + 1) * CHUNKPTS, CHUNKPTS,
                         bid & 7, bid >> 3, GATHER_BLOCKS / 8);
        } else {
            const int tiles = CHUNKPTS / 256;  // 2048
            for (int t = bid - GATHER_BLOCKS; t < tiles; t += COOP_BLOCKS - GATHER_BLOCKS)
                mlp_tile(fcur, view_dir, w0p, w1p, b0, b1, W2, b2, out,
                         actsb, s * CHUNKPTS, CHUNKPTS, t);
        }
        __threadfence();
        grid.sync();
    }
    // epilogue: ALL blocks MLP chunk 3 (buffer parity: 3&1 -> feat1)
    {
        unsigned* const fcur = ((NCHUNK - 1) & 1) ? feat1 : feat0;
        const int tiles = CHUNKPTS / 256;
        for (int t = bid; t < tiles; t += COOP_BLOCKS)
            mlp_tile(fcur, view_dir, w0p, w1p, b0, b1, W2, b2, out,
                     actsb, (NCHUNK - 1) * CHUNKPTS, CHUNKPTS, t);
    }
}

// ===================== Serial kernels (fallback path, R8 structure) ================
__global__ __launch_bounds__(256, 8) void nerf_gather_k(
    const float* __restrict__ x, const unsigned* __restrict__ tabp,
    unsigned* __restrict__ feat, int chunkbase, int chunkpts)
{
    gather_chunk(x, tabp, feat, chunkbase, chunkpts,
                 blockIdx.x & 7, blockIdx.x >> 3, gridDim.x / 8);
}

__global__ __launch_bounds__(256, 4) void nerf_mlp_k(
    const unsigned* __restrict__ feat, const float* __restrict__ view_dir,
    const unsigned short* __restrict__ w0p, const unsigned short* __restrict__ w1p,
    const float* __restrict__ b0, const float* __restrict__ b1,
    const float* __restrict__ W2, const float* __restrict__ b2,
    float* __restrict__ out, int chunkbase, int chunkpts)
{
    __shared__ __align__(16) unsigned short acts[256 * 64];
    mlp_tile(feat, view_dir, w0p, w1p, b0, b1, W2, b2, out,
             (char*)acts, chunkbase, chunkpts, blockIdx.x);
}

// ===================== Last-resort fused kernel (tiny ws) ==========================
__global__ __launch_bounds__(256, 4) void nerf_fused(
    const float* __restrict__ x, const float* __restrict__ view_dir,
    const float* __restrict__ tables,
    const float* __restrict__ W0, const float* __restrict__ b0,
    const float* __restrict__ W1, const float* __restrict__ b1,
    const float* __restrict__ W2, const float* __restrict__ b2,
    float* __restrict__ out)
{
    __shared__ __align__(16) unsigned short acts[256 * 64];
    char* const actsb = (char*)acts;
    const int tid = threadIdx.x;
    const int gid = blockIdx.x * 256 + tid;
    const float px = x[gid * 3 + 0], py = x[gid * 3 + 1], pz = x[gid * 3 + 2];

    unsigned idx[LEVELS];
    #pragma unroll
    for (int l = 0; l < LEVELS; ++l) idx[l] = hash3(px, py, pz, c_res[l]);
    float2 f[LEVELS];
    #pragma unroll
    for (int l = 0; l < LEVELS; ++l)
        f[l] = *reinterpret_cast<const float2*>(tables + ((size_t)l * HASHMAP_SIZE + idx[l]) * 2);

    unsigned fw[18];
    #pragma unroll
    for (int l = 0; l < LEVELS; ++l)
        fw[l] = (unsigned)f2bf(f[l].x) | ((unsigned)f2bf(f[l].y) << 16);
    fw[16] = (unsigned)f2bf(view_dir[gid * 3 + 0])
           | ((unsigned)f2bf(view_dir[gid * 3 + 1]) << 16);
    fw[17] = (unsigned)f2bf(view_dir[gid * 3 + 2]);
    {
        const unsigned row = (unsigned)tid;
        #pragma unroll
        for (int c = 0; c < 8; ++c) {
            int4 v;
            if (c < 4)       v = make_int4((int)fw[4*c], (int)fw[4*c+1], (int)fw[4*c+2], (int)fw[4*c+3]);
            else if (c == 4) v = make_int4((int)fw[16], (int)fw[17], 0, 0);
            else             v = make_int4(0, 0, 0, 0);
            *(int4*)(actsb + swz(row, (unsigned)(c * 16))) = v;
        }
    }
    const int lane = tid & 63;
    const int lr = lane & 15;
    const int lg = lane >> 4;
    const unsigned Rbase = (unsigned)(tid & ~63);
    #pragma unroll
    for (int layer = 0; layer < 2; ++layer) {
        const float* const Wg = layer ? W1 : W0;
        const float* const bg = layer ? b1 : b0;
        const int kmax = layer ? 64 : 35;
        bf16x8 bw[8];
        #pragma unroll
        for (int nt = 0; nt < 4; ++nt)
            #pragma unroll
            for (int ks = 0; ks < 2; ++ks)
                bw[nt * 2 + ks] = load_wfrag(Wg, 64, nt * 16 + lr, ks * 32 + lg * 8, kmax);
        #pragma unroll
        for (int rt = 0; rt < 4; ++rt) {
            bf16x8 aa[2];
            #pragma unroll
            for (int ks = 0; ks < 2; ++ks) {
                const unsigned row = Rbase + (unsigned)(rt * 16 + lr);
                aa[ks] = *(const bf16x8*)(actsb + swz(row, (unsigned)((ks * 4 + lg) * 16)));
            }
            #pragma unroll
            for (int nt = 0; nt < 4; ++nt) {
                const float bv = bg[nt * 16 + lr];
                f32x4 c = {bv, bv, bv, bv};
                c = __builtin_amdgcn_mfma_f32_16x16x32_bf16(aa[0], bw[nt * 2 + 0], c, 0, 0, 0);
                c = __builtin_amdgcn_mfma_f32_16x16x32_bf16(aa[1], bw[nt * 2 + 1], c, 0, 0, 0);
                #pragma unroll
                for (int r = 0; r < 4; ++r) {
                    const float v = fmaxf(c[r], 0.f);
                    const unsigned row = Rbase + (unsigned)(rt * 16 + lg * 4 + r);
                    const unsigned col = (unsigned)(nt * 16 + lr);
                    *(unsigned short*)(actsb + swz(row, col * 2)) = f2bf(v);
                }
            }
        }
    }
    {
        float o0 = b2[0], o1 = b2[1], o2 = b2[2], o3 = b2[3];
        const unsigned row = (unsigned)tid;
        #pragma unroll
        for (int c = 0; c < 8; ++c) {
            const bf16x8 v = *(const bf16x8*)(actsb + swz(row, (unsigned)(c * 16)));
            #pragma unroll
            for (int j = 0; j < 8; ++j) {
                const float s = __builtin_bit_cast(float, ((unsigned)(unsigned short)v[j]) << 16);
                const int k = c * 8 + j;
                o0 += s * W2[k * 4 + 0];
                o1 += s * W2[k * 4 + 1];
                o2 += s * W2[k * 4 + 2];
                o3 += s * W2[k * 4 + 3];
            }
        }
        out[(size_t)gid * 3 + 0] = 1.f / (1.f + __expf(-o0));
        out[(size_t)gid * 3 + 1] = 1.f / (1.f + __expf(-o1));
        out[(size_t)gid * 3 + 2] = 1.f / (1.f + __expf(-o2));
        out[(size_t)N_POINTS * 3 + gid] = fmaxf(o3, 0.f);
    }
}

extern "C" void kernel_launch(void* const* d_in, const int* in_sizes, int n_in,
                              void* d_out, int out_size, void* d_ws, size_t ws_size,
                              hipStream_t stream) {
    (void)in_sizes; (void)n_in; (void)out_size;
    const float* x        = (const float*)d_in[0];
    const float* view_dir = (const float*)d_in[1];
    const float* tables   = (const float*)d_in[2];
    const float* W0       = (const float*)d_in[3];
    const float* b0       = (const float*)d_in[4];
    const float* W1       = (const float*)d_in[5];
    const float* b1       = (const float*)d_in[6];
    const float* W2       = (const float*)d_in[7];
    const float* b2       = (const float*)d_in[8];
    float* out = (float*)d_out;

    const size_t TAB_BYTES = (size_t)LEVELS * HASHMAP_SIZE * 4;  // 32 MB packed bf16
    const size_t WP_BYTES  = 16384;                              // 2 x 8 KB packed weights
    const size_t CFEAT     = (size_t)CHUNKPTS * LEVELS * 4;      // 33.55 MB per chunk

    unsigned* tabp        = (unsigned*)d_ws;
    unsigned short* w0p   = (unsigned short*)((char*)d_ws + TAB_BYTES);
    unsigned short* w1p   = w0p + 4096;
    unsigned* feat        = (unsigned*)((char*)d_ws + TAB_BYTES + WP_BYTES);

    bool conv_done = false;

    // --- preferred: cooperative overlapped pipeline (needs 2-chunk feat dbuf) ---
    if (ws_size >= TAB_BYTES + WP_BYTES + 2 * CFEAT) {
        conv_tables<<<(LEVELS * HASHMAP_SIZE / 4) / 256, 256, 0, stream>>>(
            tables, tabp, W0, W1, w0p, w1p);
        conv_done = true;
        void* args[] = {(void*)&x, (void*)&view_dir, (void*)&tabp, (void*)&w0p, (void*)&w1p,
                        (void*)&b0, (void*)&b1, (void*)&W2, (void*)&b2, (void*)&out,
                        (void*)&feat};
        hipError_t e = hipLaunchCooperativeKernel((const void*)nerf_coop,
                                                  dim3(COOP_BLOCKS), dim3(256),
                                                  args, 0, stream);
        if (e == hipSuccess) return;
        // else fall through to serial path (same buffers)
    }

    // --- serial fallback (R8 structure) ---
    int nchunks = 0;
    if      (ws_size >= TAB_BYTES + WP_BYTES + (size_t)N_POINTS * 64) nchunks = 1;
    else if (ws_size >= TAB_BYTES + WP_BYTES + (size_t)N_POINTS * 32) nchunks = 2;
    else if (ws_size >= TAB_BYTES + WP_BYTES + (size_t)N_POINTS * 16) nchunks = 4;

    if (nchunks == 0) {
        nerf_fused<<<N_POINTS / 256, 256, 0, stream>>>(x, view_dir, tables,
                                                       W0, b0, W1, b1, W2, b2, out);
        return;
    }

    if (!conv_done)
        conv_tables<<<(LEVELS * HASHMAP_SIZE / 4) / 256, 256, 0, stream>>>(
            tables, tabp, W0, W1, w0p, w1p);

    const int chunkpts = N_POINTS / nchunks;
    for (int c = 0; c < nchunks; ++c) {
        const int base = c * chunkpts;
        nerf_gather_k<<<2048, 256, 0, stream>>>(x, tabp, feat, base, chunkpts);
        nerf_mlp_k<<<chunkpts / 256, 256, 0, stream>>>(feat, view_dir, w0p, w1p,
                                                       b0, b1, W2, b2, out,
                                                       base, chunkpts);
    }
}

// Round 11
// 428.530 us; speedup vs baseline: 3.9163x; 3.9163x over previous
//
#include <hip/hip_runtime.h>
#include <math.h>

#define LEVELS 16
#define HASHMAP_SIZE (1 << 19)
#define N_POINTS 2097152

typedef __attribute__((ext_vector_type(8))) short bf16x8;
typedef __attribute__((ext_vector_type(4))) float f32x4;
typedef __attribute__((ext_vector_type(4))) unsigned u32x4;

__device__ __constant__ float c_res[LEVELS] = {
    16.f, 24.f, 36.f, 54.f, 81.f, 121.f, 182.f, 273.f,
    410.f, 615.f, 922.f, 1383.f, 2075.f, 3113.f, 4670.f, 7006.f};

__device__ __forceinline__ unsigned short f2bf(float f) {
    unsigned u = __builtin_bit_cast(unsigned, f);
    u += 0x7FFFu + ((u >> 16) & 1u);   // RNE
    return (unsigned short)(u >> 16);
}
__device__ __forceinline__ unsigned cvt_pk_bf16(float a, float b) {
    unsigned r;
    asm("v_cvt_pk_bf16_f32 %0, %1, %2" : "=v"(r) : "v"(a), "v"(b));
    return r;
}

// LDS byte-swizzle (T2/G4)
__device__ __forceinline__ unsigned swz(unsigned row, unsigned colbyte) {
    return row * 128u + (colbyte ^ ((row & 7u) << 4));
}

__device__ __forceinline__ unsigned hash3(float px, float py, float pz, float r) {
    const int ix = (int)floorf(px * r);
    const int iy = (int)floorf(py * r);
    const int iz = (int)floorf(pz * r);
    const unsigned h = (unsigned)ix * 73856093u
                     ^ (unsigned)iy * 19349663u
                     ^ (unsigned)iz * 83492791u;
    return h & (unsigned)(HASHMAP_SIZE - 1);
}

__device__ __forceinline__ bf16x8 load_wfrag(const float* __restrict__ W, int ncols,
                                             int n, int k0, int kmax) {
    bf16x8 r;
    #pragma unroll
    for (int j = 0; j < 8; ++j) {
        const int k = k0 + j;
        const float v = (k < kmax) ? W[k * ncols + n] : 0.f;
        r[j] = (short)f2bf(v);
    }
    return r;
}

// ===================== Pass A0: tables f32 -> packed bf16x2 (+ weights) ==============
__global__ __launch_bounds__(256) void conv_tables(const float* __restrict__ tables,
                                                   unsigned* __restrict__ tabp,
                                                   const float* __restrict__ W0,
                                                   const float* __restrict__ W1,
                                                   unsigned short* __restrict__ w0p,
                                                   unsigned short* __restrict__ w1p) {
    const int t = blockIdx.x * 256 + threadIdx.x;
    if (blockIdx.x < 16) {
        const int i = t;
        const int n = i >> 6, k = i & 63;
        w0p[n * 64 + k] = f2bf((k < 35) ? W0[k * 64 + n] : 0.f);
        w1p[n * 64 + k] = f2bf(W1[k * 64 + n]);
    }
    const float4 a = *reinterpret_cast<const float4*>(tables + (size_t)t * 8);
    const float4 b = *reinterpret_cast<const float4*>(tables + (size_t)t * 8 + 4);
    uint4 o;
    o.x = (unsigned)f2bf(a.x) | ((unsigned)f2bf(a.y) << 16);
    o.y = (unsigned)f2bf(a.z) | ((unsigned)f2bf(a.w) << 16);
    o.z = (unsigned)f2bf(b.x) | ((unsigned)f2bf(b.y) << 16);
    o.w = (unsigned)f2bf(b.z) | ((unsigned)f2bf(b.w) << 16);
    *reinterpret_cast<uint4*>(tabp + (size_t)t * 4) = o;
}

// ===================== Pass A1: XCD-pinned gather =====================
// pair = blockIdx & 7 -> XCD (round-robin dispatch). pair p serves levels {p, p+8};
// bf16 footprint 2x2MB = 4MB = one XCD L2. 2048 blocks = exactly 8/CU co-resident.
__global__ __launch_bounds__(256, 8) void nerf_gather_k(
    const float* __restrict__ x, const unsigned* __restrict__ tabp,
    unsigned* __restrict__ feat, int chunkbase, int chunkpts)
{
    const int pair = blockIdx.x & 7;
    const int bip = blockIdx.x >> 3;
    const int nbp = gridDim.x / 8;
    const int l0 = pair, l1 = pair + 8;
    const float r0 = c_res[l0], r1 = c_res[l1];
    const int tid = threadIdx.x;
    const int groups = chunkpts >> 2;
    const int gstride = nbp * 256;
    const unsigned* __restrict__ t0 = tabp + (size_t)l0 * HASHMAP_SIZE;
    const unsigned* __restrict__ t1 = tabp + (size_t)l1 * HASHMAP_SIZE;
    for (int g = bip * 256 + tid; g < groups; g += gstride) {
        const int pl = g * 4;
        const size_t pg = (size_t)chunkbase + pl;
        const float4 xa = *(const float4*)(x + pg * 3 + 0);
        const float4 xb = *(const float4*)(x + pg * 3 + 4);
        const float4 xc = *(const float4*)(x + pg * 3 + 8);
        const unsigned iA0 = hash3(xa.x, xa.y, xa.z, r0), iB0 = hash3(xa.x, xa.y, xa.z, r1);
        const unsigned iA1 = hash3(xa.w, xb.x, xb.y, r0), iB1 = hash3(xa.w, xb.x, xb.y, r1);
        const unsigned iA2 = hash3(xb.z, xb.w, xc.x, r0), iB2 = hash3(xb.z, xb.w, xc.x, r1);
        const unsigned iA3 = hash3(xc.y, xc.z, xc.w, r0), iB3 = hash3(xc.y, xc.z, xc.w, r1);
        u32x4 gA, gB;
        gA.x = t0[iA0]; gA.y = t0[iA1]; gA.z = t0[iA2]; gA.w = t0[iA3];
        gB.x = t1[iB0]; gB.y = t1[iB1]; gB.z = t1[iB2]; gB.w = t1[iB3];
        __builtin_nontemporal_store(gA, (u32x4*)(feat + (size_t)l0 * chunkpts + pl));
        __builtin_nontemporal_store(gB, (u32x4*)(feat + (size_t)l1 * chunkpts + pl));
    }
}

// ===================== Pass B: MLP on MFMA (all three layers) =====================
__global__ __launch_bounds__(256, 5) void nerf_mlp_k(
    const unsigned* __restrict__ feat, const float* __restrict__ view_dir,
    const unsigned short* __restrict__ w0p, const unsigned short* __restrict__ w1p,
    const float* __restrict__ b0, const float* __restrict__ b1,
    const float* __restrict__ W2, const float* __restrict__ b2,
    float* __restrict__ out, int chunkbase, int chunkpts)
{
    __shared__ __align__(16) unsigned short acts[256 * 64]; // 32 KB -> 5 blocks/CU
    char* const actsb = (char*)acts;

    const int tid = threadIdx.x;
    const int gl = blockIdx.x * 256 + tid;
    const size_t gid = (size_t)chunkbase + gl;

    unsigned fw[18];
    #pragma unroll
    for (int l = 0; l < LEVELS; ++l)
        fw[l] = feat[(size_t)l * chunkpts + gl];
    fw[16] = (unsigned)f2bf(view_dir[gid * 3 + 0])
           | ((unsigned)f2bf(view_dir[gid * 3 + 1]) << 16);
    fw[17] = (unsigned)f2bf(view_dir[gid * 3 + 2]);

    {
        const unsigned row = (unsigned)tid;
        #pragma unroll
        for (int c = 0; c < 8; ++c) {
            int4 v;
            if (c < 4)       v = make_int4((int)fw[4*c], (int)fw[4*c+1], (int)fw[4*c+2], (int)fw[4*c+3]);
            else if (c == 4) v = make_int4((int)fw[16], (int)fw[17], 0, 0);
            else             v = make_int4(0, 0, 0, 0);
            *(int4*)(actsb + swz(row, (unsigned)(c * 16))) = v;
        }
    }
    // No barriers: wave w touches only rows [64w, 64w+64).

    const int lane = tid & 63;
    const int lr = lane & 15;
    const int lg = lane >> 4;
    const unsigned Rbase = (unsigned)(tid & ~63);

    #pragma unroll
    for (int layer = 0; layer < 2; ++layer) {
        const unsigned short* const Wp = layer ? w1p : w0p;
        const float* const bg = layer ? b1 : b0;

        bf16x8 bw[8];
        #pragma unroll
        for (int nt = 0; nt < 4; ++nt)
            #pragma unroll
            for (int ks = 0; ks < 2; ++ks)
                bw[nt * 2 + ks] = *(const bf16x8*)(Wp + (nt * 16 + lr) * 64 + (ks * 32 + lg * 8));

        #pragma unroll
        for (int rt = 0; rt < 4; ++rt) {
            bf16x8 aa[2];
            #pragma unroll
            for (int ks = 0; ks < 2; ++ks) {
                const unsigned row = Rbase + (unsigned)(rt * 16 + lr);
                aa[ks] = *(const bf16x8*)(actsb + swz(row, (unsigned)((ks * 4 + lg) * 16)));
            }
            #pragma unroll
            for (int nt = 0; nt < 4; ++nt) {
                const float bv = bg[nt * 16 + lr];
                f32x4 c = {bv, bv, bv, bv};
                c = __builtin_amdgcn_mfma_f32_16x16x32_bf16(aa[0], bw[nt * 2 + 0], c, 0, 0, 0);
                c = __builtin_amdgcn_mfma_f32_16x16x32_bf16(aa[1], bw[nt * 2 + 1], c, 0, 0, 0);
                const unsigned u01 = cvt_pk_bf16(fmaxf(c[0], 0.f), fmaxf(c[1], 0.f));
                const unsigned u23 = cvt_pk_bf16(fmaxf(c[2], 0.f), fmaxf(c[3], 0.f));
                const unsigned col = (unsigned)(nt * 16 + lr);
                const unsigned rbase = Rbase + (unsigned)(rt * 16 + lg * 4);
                *(unsigned short*)(actsb + swz(rbase + 0, col * 2)) = (unsigned short)u01;
                *(unsigned short*)(actsb + swz(rbase + 1, col * 2)) = (unsigned short)(u01 >> 16);
                *(unsigned short*)(actsb + swz(rbase + 2, col * 2)) = (unsigned short)u23;
                *(unsigned short*)(actsb + swz(rbase + 3, col * 2)) = (unsigned short)(u23 >> 16);
            }
        }
    }

    // Layer 2 (64->4) on MFMA; bounce via wave-own LDS rows for coalesced stores
    {
        const bool valid = (lr < 4);
        bf16x8 bw2[2];
        #pragma unroll
        for (int ks = 0; ks < 2; ++ks) {
            if (valid) bw2[ks] = load_wfrag(W2, 4, lr, ks * 32 + lg * 8, 64);
            else       bw2[ks] = bf16x8{0,0,0,0,0,0,0,0};
        }
        const float bc = valid ? b2[lr] : 0.f;

        #pragma unroll
        for (int rt = 0; rt < 4; ++rt) {
            bf16x8 aa[2];
            #pragma unroll
            for (int ks = 0; ks < 2; ++ks) {
                const unsigned row = Rbase + (unsigned)(rt * 16 + lr);
                aa[ks] = *(const bf16x8*)(actsb + swz(row, (unsigned)((ks * 4 + lg) * 16)));
            }
            f32x4 c = {bc, bc, bc, bc};
            c = __builtin_amdgcn_mfma_f32_16x16x32_bf16(aa[0], bw2[0], c, 0, 0, 0);
            c = __builtin_amdgcn_mfma_f32_16x16x32_bf16(aa[1], bw2[1], c, 0, 0, 0);
            if (valid) {
                #pragma unroll
                for (int r = 0; r < 4; ++r) {
                    const unsigned row = Rbase + (unsigned)(rt * 16 + lg * 4 + r);
                    *(float*)(actsb + row * 128u + ((row & 7u) << 4) + (unsigned)lr * 4u) = c[r];
                }
            }
        }
        const unsigned row = (unsigned)tid;
        const f32x4 o = *(const f32x4*)(actsb + row * 128u + ((row & 7u) << 4));
        out[gid * 3 + 0] = 1.f / (1.f + __expf(-o[0]));
        out[gid * 3 + 1] = 1.f / (1.f + __expf(-o[1]));
        out[gid * 3 + 2] = 1.f / (1.f + __expf(-o[2]));
        out[(size_t)N_POINTS * 3 + gid] = fmaxf(o[3], 0.f);
    }
}

// ===================== Last-resort fused kernel (tiny ws) ==========================
__global__ __launch_bounds__(256, 4) void nerf_fused(
    const float* __restrict__ x, const float* __restrict__ view_dir,
    const float* __restrict__ tables,
    const float* __restrict__ W0, const float* __restrict__ b0,
    const float* __restrict__ W1, const float* __restrict__ b1,
    const float* __restrict__ W2, const float* __restrict__ b2,
    float* __restrict__ out)
{
    __shared__ __align__(16) unsigned short acts[256 * 64];
    char* const actsb = (char*)acts;
    const int tid = threadIdx.x;
    const int gid = blockIdx.x * 256 + tid;
    const float px = x[gid * 3 + 0], py = x[gid * 3 + 1], pz = x[gid * 3 + 2];

    unsigned idx[LEVELS];
    #pragma unroll
    for (int l = 0; l < LEVELS; ++l) idx[l] = hash3(px, py, pz, c_res[l]);
    float2 f[LEVELS];
    #pragma unroll
    for (int l = 0; l < LEVELS; ++l)
        f[l] = *reinterpret_cast<const float2*>(tables + ((size_t)l * HASHMAP_SIZE + idx[l]) * 2);

    unsigned fw[18];
    #pragma unroll
    for (int l = 0; l < LEVELS; ++l)
        fw[l] = (unsigned)f2bf(f[l].x) | ((unsigned)f2bf(f[l].y) << 16);
    fw[16] = (unsigned)f2bf(view_dir[gid * 3 + 0])
           | ((unsigned)f2bf(view_dir[gid * 3 + 1]) << 16);
    fw[17] = (unsigned)f2bf(view_dir[gid * 3 + 2]);
    {
        const unsigned row = (unsigned)tid;
        #pragma unroll
        for (int c = 0; c < 8; ++c) {
            int4 v;
            if (c < 4)       v = make_int4((int)fw[4*c], (int)fw[4*c+1], (int)fw[4*c+2], (int)fw[4*c+3]);
            else if (c == 4) v = make_int4((int)fw[16], (int)fw[17], 0, 0);
            else             v = make_int4(0, 0, 0, 0);
            *(int4*)(actsb + swz(row, (unsigned)(c * 16))) = v;
        }
    }
    const int lane = tid & 63;
    const int lr = lane & 15;
    const int lg = lane >> 4;
    const unsigned Rbase = (unsigned)(tid & ~63);
    #pragma unroll
    for (int layer = 0; layer < 2; ++layer) {
        const float* const Wg = layer ? W1 : W0;
        const float* const bg = layer ? b1 : b0;
        const int kmax = layer ? 64 : 35;
        bf16x8 bw[8];
        #pragma unroll
        for (int nt = 0; nt < 4; ++nt)
            #pragma unroll
            for (int ks = 0; ks < 2; ++ks)
                bw[nt * 2 + ks] = load_wfrag(Wg, 64, nt * 16 + lr, ks * 32 + lg * 8, kmax);
        #pragma unroll
        for (int rt = 0; rt < 4; ++rt) {
            bf16x8 aa[2];
            #pragma unroll
            for (int ks = 0; ks < 2; ++ks) {
                const unsigned row = Rbase + (unsigned)(rt * 16 + lr);
                aa[ks] = *(const bf16x8*)(actsb + swz(row, (unsigned)((ks * 4 + lg) * 16)));
            }
            #pragma unroll
            for (int nt = 0; nt < 4; ++nt) {
                const float bv = bg[nt * 16 + lr];
                f32x4 c = {bv, bv, bv, bv};
                c = __builtin_amdgcn_mfma_f32_16x16x32_bf16(aa[0], bw[nt * 2 + 0], c, 0, 0, 0);
                c = __builtin_amdgcn_mfma_f32_16x16x32_bf16(aa[1], bw[nt * 2 + 1], c, 0, 0, 0);
                #pragma unroll
                for (int r = 0; r < 4; ++r) {
                    const float v = fmaxf(c[r], 0.f);
                    const unsigned row = Rbase + (unsigned)(rt * 16 + lg * 4 + r);
                    const unsigned col = (unsigned)(nt * 16 + lr);
                    *(unsigned short*)(actsb + swz(row, col * 2)) = f2bf(v);
                }
            }
        }
    }
    {
        float o0 = b2[0], o1 = b2[1], o2 = b2[2], o3 = b2[3];
        const unsigned row = (unsigned)tid;
        #pragma unroll
        for (int c = 0; c < 8; ++c) {
            const bf16x8 v = *(const bf16x8*)(actsb + swz(row, (unsigned)(c * 16)));
            #pragma unroll
            for (int j = 0; j < 8; ++j) {
                const float s = __builtin_bit_cast(float, ((unsigned)(unsigned short)v[j]) << 16);
                const int k = c * 8 + j;
                o0 += s * W2[k * 4 + 0];
                o1 += s * W2[k * 4 + 1];
                o2 += s * W2[k * 4 + 2];
                o3 += s * W2[k * 4 + 3];
            }
        }
        out[(size_t)gid * 3 + 0] = 1.f / (1.f + __expf(-o0));
        out[(size_t)gid * 3 + 1] = 1.f / (1.f + __expf(-o1));
        out[(size_t)gid * 3 + 2] = 1.f / (1.f + __expf(-o2));
        out[(size_t)N_POINTS * 3 + gid] = fmaxf(o3, 0.f);
    }
}

extern "C" void kernel_launch(void* const* d_in, const int* in_sizes, int n_in,
                              void* d_out, int out_size, void* d_ws, size_t ws_size,
                              hipStream_t stream) {
    (void)in_sizes; (void)n_in; (void)out_size;
    const float* x        = (const float*)d_in[0];
    const float* view_dir = (const float*)d_in[1];
    const float* tables   = (const float*)d_in[2];
    const float* W0       = (const float*)d_in[3];
    const float* b0       = (const float*)d_in[4];
    const float* W1       = (const float*)d_in[5];
    const float* b1       = (const float*)d_in[6];
    const float* W2       = (const float*)d_in[7];
    const float* b2       = (const float*)d_in[8];
    float* out = (float*)d_out;

    const size_t TAB_BYTES = (size_t)LEVELS * HASHMAP_SIZE * 4;  // 32 MB packed bf16
    const size_t WP_BYTES  = 16384;                              // 2 x 8 KB packed weights

    int nchunks = 0;
    if      (ws_size >= TAB_BYTES + WP_BYTES + (size_t)N_POINTS * 64) nchunks = 1;
    else if (ws_size >= TAB_BYTES + WP_BYTES + (size_t)N_POINTS * 32) nchunks = 2;
    else if (ws_size >= TAB_BYTES + WP_BYTES + (size_t)N_POINTS * 16) nchunks = 4;

    if (nchunks == 0) {
        nerf_fused<<<N_POINTS / 256, 256, 0, stream>>>(x, view_dir, tables,
                                                       W0, b0, W1, b1, W2, b2, out);
        return;
    }

    unsigned* tabp        = (unsigned*)d_ws;
    unsigned short* w0p   = (unsigned short*)((char*)d_ws + TAB_BYTES);
    unsigned short* w1p   = w0p + 4096;
    unsigned* feat        = (unsigned*)((char*)d_ws + TAB_BYTES + WP_BYTES);
    const int chunkpts = N_POINTS / nchunks;

    conv_tables<<<(LEVELS * HASHMAP_SIZE / 4) / 256, 256, 0, stream>>>(
        tables, tabp, W0, W1, w0p, w1p);

    for (int c = 0; c < nchunks; ++c) {
        const int base = c * chunkpts;
        nerf_gather_k<<<2048, 256, 0, stream>>>(x, tabp, feat, base, chunkpts);
        nerf_mlp_k<<<chunkpts / 256, 256, 0, stream>>>(feat, view_dir, w0p, w1p,
                                                       b0, b1, W2, b2, out,
                                                       base, chunkpts);
    }
}

// Round 12
// 327.819 us; speedup vs baseline: 5.1195x; 1.3072x over previous
//
#include <hip/hip_runtime.h>
#include <math.h>

#define LEVELS 16
#define HASHMAP_SIZE (1 << 19)
#define N_POINTS 2097152

typedef __attribute__((ext_vector_type(8))) short bf16x8;
typedef __attribute__((ext_vector_type(4))) float f32x4;
typedef __attribute__((ext_vector_type(4))) unsigned u32x4;

__device__ __constant__ float c_res[LEVELS] = {
    16.f, 24.f, 36.f, 54.f, 81.f, 121.f, 182.f, 273.f,
    410.f, 615.f, 922.f, 1383.f, 2075.f, 3113.f, 4670.f, 7006.f};

__device__ __forceinline__ unsigned short f2bf(float f) {
    unsigned u = __builtin_bit_cast(unsigned, f);
    u += 0x7FFFu + ((u >> 16) & 1u);   // RNE
    return (unsigned short)(u >> 16);
}
__device__ __forceinline__ unsigned cvt_pk_bf16(float a, float b) {
    unsigned r;
    asm("v_cvt_pk_bf16_f32 %0, %1, %2" : "=v"(r) : "v"(a), "v"(b));
    return r;
}

// LDS byte-swizzle (T2/G4)
__device__ __forceinline__ unsigned swz(unsigned row, unsigned colbyte) {
    return row * 128u + (colbyte ^ ((row & 7u) << 4));
}

__device__ __forceinline__ unsigned hash3(float px, float py, float pz, float r) {
    const int ix = (int)floorf(px * r);
    const int iy = (int)floorf(py * r);
    const int iz = (int)floorf(pz * r);
    const unsigned h = (unsigned)ix * 73856093u
                     ^ (unsigned)iy * 19349663u
                     ^ (unsigned)iz * 83492791u;
    return h & (unsigned)(HASHMAP_SIZE - 1);
}

__device__ __forceinline__ bf16x8 load_wfrag(const float* __restrict__ W, int ncols,
                                             int n, int k0, int kmax) {
    bf16x8 r;
    #pragma unroll
    for (int j = 0; j < 8; ++j) {
        const int k = k0 + j;
        const float v = (k < kmax) ? W[k * ncols + n] : 0.f;
        r[j] = (short)f2bf(v);
    }
    return r;
}

// ===================== Pass A0: tables f32 -> packed bf16x2 (+ weights) ==============
__global__ __launch_bounds__(256) void conv_tables(const float* __restrict__ tables,
                                                   unsigned* __restrict__ tabp,
                                                   const float* __restrict__ W0,
                                                   const float* __restrict__ W1,
                                                   unsigned short* __restrict__ w0p,
                                                   unsigned short* __restrict__ w1p) {
    const int t = blockIdx.x * 256 + threadIdx.x;
    if (blockIdx.x < 16) {
        const int i = t;
        const int n = i >> 6, k = i & 63;
        w0p[n * 64 + k] = f2bf((k < 35) ? W0[k * 64 + n] : 0.f);
        w1p[n * 64 + k] = f2bf(W1[k * 64 + n]);
    }
    const float4 a = *reinterpret_cast<const float4*>(tables + (size_t)t * 8);
    const float4 b = *reinterpret_cast<const float4*>(tables + (size_t)t * 8 + 4);
    uint4 o;
    o.x = (unsigned)f2bf(a.x) | ((unsigned)f2bf(a.y) << 16);
    o.y = (unsigned)f2bf(a.z) | ((unsigned)f2bf(a.w) << 16);
    o.z = (unsigned)f2bf(b.x) | ((unsigned)f2bf(b.y) << 16);
    o.w = (unsigned)f2bf(b.z) | ((unsigned)f2bf(b.w) << 16);
    *reinterpret_cast<uint4*>(tabp + (size_t)t * 4) = o;
}

// ===================== Pass A1: XCD-pinned gather =====================
// pair = blockIdx & 7 -> XCD (round-robin dispatch). pair p serves levels {p, p+8};
// bf16 footprint 2x2MB = 4MB = one XCD L2. 2048 blocks = exactly 8/CU co-resident.
__global__ __launch_bounds__(256, 8) void nerf_gather_k(
    const float* __restrict__ x, const unsigned* __restrict__ tabp,
    unsigned* __restrict__ feat, int chunkbase, int chunkpts)
{
    const int pair = blockIdx.x & 7;
    const int bip = blockIdx.x >> 3;
    const int nbp = gridDim.x / 8;
    const int l0 = pair, l1 = pair + 8;
    const float r0 = c_res[l0], r1 = c_res[l1];
    const int tid = threadIdx.x;
    const int groups = chunkpts >> 2;
    const int gstride = nbp * 256;
    const unsigned* __restrict__ t0 = tabp + (size_t)l0 * HASHMAP_SIZE;
    const unsigned* __restrict__ t1 = tabp + (size_t)l1 * HASHMAP_SIZE;
    for (int g = bip * 256 + tid; g < groups; g += gstride) {
        const int pl = g * 4;
        const size_t pg = (size_t)chunkbase + pl;
        const float4 xa = *(const float4*)(x + pg * 3 + 0);
        const float4 xb = *(const float4*)(x + pg * 3 + 4);
        const float4 xc = *(const float4*)(x + pg * 3 + 8);
        const unsigned iA0 = hash3(xa.x, xa.y, xa.z, r0), iB0 = hash3(xa.x, xa.y, xa.z, r1);
        const unsigned iA1 = hash3(xa.w, xb.x, xb.y, r0), iB1 = hash3(xa.w, xb.x, xb.y, r1);
        const unsigned iA2 = hash3(xb.z, xb.w, xc.x, r0), iB2 = hash3(xb.z, xb.w, xc.x, r1);
        const unsigned iA3 = hash3(xc.y, xc.z, xc.w, r0), iB3 = hash3(xc.y, xc.z, xc.w, r1);
        u32x4 gA, gB;
        gA.x = t0[iA0]; gA.y = t0[iA1]; gA.z = t0[iA2]; gA.w = t0[iA3];
        gB.x = t1[iB0]; gB.y = t1[iB1]; gB.z = t1[iB2]; gB.w = t1[iB3];
        __builtin_nontemporal_store(gA, (u32x4*)(feat + (size_t)l0 * chunkpts + pl));
        __builtin_nontemporal_store(gB, (u32x4*)(feat + (size_t)l1 * chunkpts + pl));
    }
}

// ===================== Pass B: MLP on MFMA (all three layers) =====================
__global__ __launch_bounds__(256, 4) void nerf_mlp_k(
    const unsigned* __restrict__ feat, const float* __restrict__ view_dir,
    const unsigned short* __restrict__ w0p, const unsigned short* __restrict__ w1p,
    const float* __restrict__ b0, const float* __restrict__ b1,
    const float* __restrict__ W2, const float* __restrict__ b2,
    float* __restrict__ out, int chunkbase, int chunkpts)
{
    __shared__ __align__(16) unsigned short acts[256 * 64]; // 32 KB
    char* const actsb = (char*)acts;

    const int tid = threadIdx.x;
    const int gl = blockIdx.x * 256 + tid;
    const size_t gid = (size_t)chunkbase + gl;

    unsigned fw[18];
    #pragma unroll
    for (int l = 0; l < LEVELS; ++l)
        fw[l] = feat[(size_t)l * chunkpts + gl];
    fw[16] = (unsigned)f2bf(view_dir[gid * 3 + 0])
           | ((unsigned)f2bf(view_dir[gid * 3 + 1]) << 16);
    fw[17] = (unsigned)f2bf(view_dir[gid * 3 + 2]);

    {
        const unsigned row = (unsigned)tid;
        #pragma unroll
        for (int c = 0; c < 8; ++c) {
            int4 v;
            if (c < 4)       v = make_int4((int)fw[4*c], (int)fw[4*c+1], (int)fw[4*c+2], (int)fw[4*c+3]);
            else if (c == 4) v = make_int4((int)fw[16], (int)fw[17], 0, 0);
            else             v = make_int4(0, 0, 0, 0);
            *(int4*)(actsb + swz(row, (unsigned)(c * 16))) = v;
        }
    }
    // No barriers: wave w touches only rows [64w, 64w+64).

    const int lane = tid & 63;
    const int lr = lane & 15;
    const int lg = lane >> 4;
    const unsigned Rbase = (unsigned)(tid & ~63);

    #pragma unroll
    for (int layer = 0; layer < 2; ++layer) {
        const unsigned short* const Wp = layer ? w1p : w0p;
        const float* const bg = layer ? b1 : b0;

        bf16x8 bw[8];
        #pragma unroll
        for (int nt = 0; nt < 4; ++nt)
            #pragma unroll
            for (int ks = 0; ks < 2; ++ks)
                bw[nt * 2 + ks] = *(const bf16x8*)(Wp + (nt * 16 + lr) * 64 + (ks * 32 + lg * 8));

        #pragma unroll
        for (int rt = 0; rt < 4; ++rt) {
            bf16x8 aa[2];
            #pragma unroll
            for (int ks = 0; ks < 2; ++ks) {
                const unsigned row = Rbase + (unsigned)(rt * 16 + lr);
                aa[ks] = *(const bf16x8*)(actsb + swz(row, (unsigned)((ks * 4 + lg) * 16)));
            }
            #pragma unroll
            for (int nt = 0; nt < 4; ++nt) {
                const float bv = bg[nt * 16 + lr];
                f32x4 c = {bv, bv, bv, bv};
                c = __builtin_amdgcn_mfma_f32_16x16x32_bf16(aa[0], bw[nt * 2 + 0], c, 0, 0, 0);
                c = __builtin_amdgcn_mfma_f32_16x16x32_bf16(aa[1], bw[nt * 2 + 1], c, 0, 0, 0);
                const unsigned u01 = cvt_pk_bf16(fmaxf(c[0], 0.f), fmaxf(c[1], 0.f));
                const unsigned u23 = cvt_pk_bf16(fmaxf(c[2], 0.f), fmaxf(c[3], 0.f));
                const unsigned col = (unsigned)(nt * 16 + lr);
                const unsigned rbase = Rbase + (unsigned)(rt * 16 + lg * 4);
                *(unsigned short*)(actsb + swz(rbase + 0, col * 2)) = (unsigned short)u01;
                *(unsigned short*)(actsb + swz(rbase + 1, col * 2)) = (unsigned short)(u01 >> 16);
                *(unsigned short*)(actsb + swz(rbase + 2, col * 2)) = (unsigned short)u23;
                *(unsigned short*)(actsb + swz(rbase + 3, col * 2)) = (unsigned short)(u23 >> 16);
            }
        }
    }

    // Layer 2 (64->4) on MFMA; bounce via wave-own LDS rows for coalesced stores
    {
        const bool valid = (lr < 4);
        bf16x8 bw2[2];
        #pragma unroll
        for (int ks = 0; ks < 2; ++ks) {
            if (valid) bw2[ks] = load_wfrag(W2, 4, lr, ks * 32 + lg * 8, 64);
            else       bw2[ks] = bf16x8{0,0,0,0,0,0,0,0};
        }
        const float bc = valid ? b2[lr] : 0.f;

        #pragma unroll
        for (int rt = 0; rt < 4; ++rt) {
            bf16x8 aa[2];
            #pragma unroll
            for (int ks = 0; ks < 2; ++ks) {
                const unsigned row = Rbase + (unsigned)(rt * 16 + lr);
                aa[ks] = *(const bf16x8*)(actsb + swz(row, (unsigned)((ks * 4 + lg) * 16)));
            }
            f32x4 c = {bc, bc, bc, bc};
            c = __builtin_amdgcn_mfma_f32_16x16x32_bf16(aa[0], bw2[0], c, 0, 0, 0);
            c = __builtin_amdgcn_mfma_f32_16x16x32_bf16(aa[1], bw2[1], c, 0, 0, 0);
            if (valid) {
                #pragma unroll
                for (int r = 0; r < 4; ++r) {
                    const unsigned row = Rbase + (unsigned)(rt * 16 + lg * 4 + r);
                    *(float*)(actsb + row * 128u + ((row & 7u) << 4) + (unsigned)lr * 4u) = c[r];
                }
            }
        }
        const unsigned row = (unsigned)tid;
        const f32x4 o = *(const f32x4*)(actsb + row * 128u + ((row & 7u) << 4));
        out[gid * 3 + 0] = 1.f / (1.f + __expf(-o[0]));
        out[gid * 3 + 1] = 1.f / (1.f + __expf(-o[1]));
        out[gid * 3 + 2] = 1.f / (1.f + __expf(-o[2]));
        out[(size_t)N_POINTS * 3 + gid] = fmaxf(o[3], 0.f);
    }
}

// ===================== Last-resort fused kernel (tiny ws) ==========================
__global__ __launch_bounds__(256, 4) void nerf_fused(
    const float* __restrict__ x, const float* __restrict__ view_dir,
    const float* __restrict__ tables,
    const float* __restrict__ W0, const float* __restrict__ b0,
    const float* __restrict__ W1, const float* __restrict__ b1,
    const float* __restrict__ W2, const float* __restrict__ b2,
    float* __restrict__ out)
{
    __shared__ __align__(16) unsigned short acts[256 * 64];
    char* const actsb = (char*)acts;
    const int tid = threadIdx.x;
    const int gid = blockIdx.x * 256 + tid;
    const float px = x[gid * 3 + 0], py = x[gid * 3 + 1], pz = x[gid * 3 + 2];

    unsigned idx[LEVELS];
    #pragma unroll
    for (int l = 0; l < LEVELS; ++l) idx[l] = hash3(px, py, pz, c_res[l]);
    float2 f[LEVELS];
    #pragma unroll
    for (int l = 0; l < LEVELS; ++l)
        f[l] = *reinterpret_cast<const float2*>(tables + ((size_t)l * HASHMAP_SIZE + idx[l]) * 2);

    unsigned fw[18];
    #pragma unroll
    for (int l = 0; l < LEVELS; ++l)
        fw[l] = (unsigned)f2bf(f[l].x) | ((unsigned)f2bf(f[l].y) << 16);
    fw[16] = (unsigned)f2bf(view_dir[gid * 3 + 0])
           | ((unsigned)f2bf(view_dir[gid * 3 + 1]) << 16);
    fw[17] = (unsigned)f2bf(view_dir[gid * 3 + 2]);
    {
        const unsigned row = (unsigned)tid;
        #pragma unroll
        for (int c = 0; c < 8; ++c) {
            int4 v;
            if (c < 4)       v = make_int4((int)fw[4*c], (int)fw[4*c+1], (int)fw[4*c+2], (int)fw[4*c+3]);
            else if (c == 4) v = make_int4((int)fw[16], (int)fw[17], 0, 0);
            else             v = make_int4(0, 0, 0, 0);
            *(int4*)(actsb + swz(row, (unsigned)(c * 16))) = v;
        }
    }
    const int lane = tid & 63;
    const int lr = lane & 15;
    const int lg = lane >> 4;
    const unsigned Rbase = (unsigned)(tid & ~63);
    #pragma unroll
    for (int layer = 0; layer < 2; ++layer) {
        const float* const Wg = layer ? W1 : W0;
        const float* const bg = layer ? b1 : b0;
        const int kmax = layer ? 64 : 35;
        bf16x8 bw[8];
        #pragma unroll
        for (int nt = 0; nt < 4; ++nt)
            #pragma unroll
            for (int ks = 0; ks < 2; ++ks)
                bw[nt * 2 + ks] = load_wfrag(Wg, 64, nt * 16 + lr, ks * 32 + lg * 8, kmax);
        #pragma unroll
        for (int rt = 0; rt < 4; ++rt) {
            bf16x8 aa[2];
            #pragma unroll
            for (int ks = 0; ks < 2; ++ks) {
                const unsigned row = Rbase + (unsigned)(rt * 16 + lr);
                aa[ks] = *(const bf16x8*)(actsb + swz(row, (unsigned)((ks * 4 + lg) * 16)));
            }
            #pragma unroll
            for (int nt = 0; nt < 4; ++nt) {
                const float bv = bg[nt * 16 + lr];
                f32x4 c = {bv, bv, bv, bv};
                c = __builtin_amdgcn_mfma_f32_16x16x32_bf16(aa[0], bw[nt * 2 + 0], c, 0, 0, 0);
                c = __builtin_amdgcn_mfma_f32_16x16x32_bf16(aa[1], bw[nt * 2 + 1], c, 0, 0, 0);
                #pragma unroll
                for (int r = 0; r < 4; ++r) {
                    const float v = fmaxf(c[r], 0.f);
                    const unsigned row = Rbase + (unsigned)(rt * 16 + lg * 4 + r);
                    const unsigned col = (unsigned)(nt * 16 + lr);
                    *(unsigned short*)(actsb + swz(row, col * 2)) = f2bf(v);
                }
            }
        }
    }
    {
        float o0 = b2[0], o1 = b2[1], o2 = b2[2], o3 = b2[3];
        const unsigned row = (unsigned)tid;
        #pragma unroll
        for (int c = 0; c < 8; ++c) {
            const bf16x8 v = *(const bf16x8*)(actsb + swz(row, (unsigned)(c * 16)));
            #pragma unroll
            for (int j = 0; j < 8; ++j) {
                const float s = __builtin_bit_cast(float, ((unsigned)(unsigned short)v[j]) << 16);
                const int k = c * 8 + j;
                o0 += s * W2[k * 4 + 0];
                o1 += s * W2[k * 4 + 1];
                o2 += s * W2[k * 4 + 2];
                o3 += s * W2[k * 4 + 3];
            }
        }
        out[(size_t)gid * 3 + 0] = 1.f / (1.f + __expf(-o0));
        out[(size_t)gid * 3 + 1] = 1.f / (1.f + __expf(-o1));
        out[(size_t)gid * 3 + 2] = 1.f / (1.f + __expf(-o2));
        out[(size_t)N_POINTS * 3 + gid] = fmaxf(o3, 0.f);
    }
}

extern "C" void kernel_launch(void* const* d_in, const int* in_sizes, int n_in,
                              void* d_out, int out_size, void* d_ws, size_t ws_size,
                              hipStream_t stream) {
    (void)in_sizes; (void)n_in; (void)out_size;
    const float* x        = (const float*)d_in[0];
    const float* view_dir = (const float*)d_in[1];
    const float* tables   = (const float*)d_in[2];
    const float* W0       = (const float*)d_in[3];
    const float* b0       = (const float*)d_in[4];
    const float* W1       = (const float*)d_in[5];
    const float* b1       = (const float*)d_in[6];
    const float* W2       = (const float*)d_in[7];
    const float* b2       = (const float*)d_in[8];
    float* out = (float*)d_out;

    const size_t TAB_BYTES = (size_t)LEVELS * HASHMAP_SIZE * 4;  // 32 MB packed bf16
    const size_t WP_BYTES  = 16384;                              // 2 x 8 KB packed weights

    int nchunks = 0;
    if      (ws_size >= TAB_BYTES + WP_BYTES + (size_t)N_POINTS * 64) nchunks = 1;
    else if (ws_size >= TAB_BYTES + WP_BYTES + (size_t)N_POINTS * 32) nchunks = 2;
    else if (ws_size >= TAB_BYTES + WP_BYTES + (size_t)N_POINTS * 16) nchunks = 4;

    if (nchunks == 0) {
        nerf_fused<<<N_POINTS / 256, 256, 0, stream>>>(x, view_dir, tables,
                                                       W0, b0, W1, b1, W2, b2, out);
        return;
    }

    unsigned* tabp        = (unsigned*)d_ws;
    unsigned short* w0p   = (unsigned short*)((char*)d_ws + TAB_BYTES);
    unsigned short* w1p   = w0p + 4096;
    unsigned* feat        = (unsigned*)((char*)d_ws + TAB_BYTES + WP_BYTES);
    const int chunkpts = N_POINTS / nchunks;

    conv_tables<<<(LEVELS * HASHMAP_SIZE / 4) / 256, 256, 0, stream>>>(
        tables, tabp, W0, W1, w0p, w1p);

    for (int c = 0; c < nchunks; ++c) {
        const int base = c * chunkpts;
        nerf_gather_k<<<2048, 256, 0, stream>>>(x, tabp, feat, base, chunkpts);
        nerf_mlp_k<<<chunkpts / 256, 256, 0, stream>>>(feat, view_dir, w0p, w1p,
                                                       b0, b1, W2, b2, out,
                                                       base, chunkpts);
    }
}

// Round 13
// 296.343 us; speedup vs baseline: 5.6632x; 1.1062x over previous
//
#include <hip/hip_runtime.h>
#include <math.h>

#define LEVELS 16
#define HASHMAP_SIZE (1 << 19)
#define N_POINTS 2097152

typedef __attribute__((ext_vector_type(8))) short bf16x8;
typedef __attribute__((ext_vector_type(4))) float f32x4;
typedef __attribute__((ext_vector_type(4))) unsigned u32x4;
typedef __attribute__((ext_vector_type(2))) unsigned u32x2;

__device__ __constant__ float c_res[LEVELS] = {
    16.f, 24.f, 36.f, 54.f, 81.f, 121.f, 182.f, 273.f,
    410.f, 615.f, 922.f, 1383.f, 2075.f, 3113.f, 4670.f, 7006.f};

__device__ __forceinline__ unsigned short f2bf(float f) {
    unsigned u = __builtin_bit_cast(unsigned, f);
    u += 0x7FFFu + ((u >> 16) & 1u);   // RNE
    return (unsigned short)(u >> 16);
}
__device__ __forceinline__ unsigned cvt_pk_bf16(float a, float b) {
    unsigned r;
    asm("v_cvt_pk_bf16_f32 %0, %1, %2" : "=v"(r) : "v"(a), "v"(b));
    return r;
}

// LDS byte-swizzle (T2/G4)
__device__ __forceinline__ unsigned swz(unsigned row, unsigned colbyte) {
    return row * 128u + (colbyte ^ ((row & 7u) << 4));
}

__device__ __forceinline__ unsigned hash3(float px, float py, float pz, float r) {
    const int ix = (int)floorf(px * r);
    const int iy = (int)floorf(py * r);
    const int iz = (int)floorf(pz * r);
    const unsigned h = (unsigned)ix * 73856093u
                     ^ (unsigned)iy * 19349663u
                     ^ (unsigned)iz * 83492791u;
    return h & (unsigned)(HASHMAP_SIZE - 1);
}

__device__ __forceinline__ bf16x8 load_wfrag(const float* __restrict__ W, int ncols,
                                             int n, int k0, int kmax) {
    bf16x8 r;
    #pragma unroll
    for (int j = 0; j < 8; ++j) {
        const int k = k0 + j;
        const float v = (k < kmax) ? W[k * ncols + n] : 0.f;
        r[j] = (short)f2bf(v);
    }
    return r;
}

// ===================== Pass A0: tables f32 -> packed bf16x2 (+ weights) ==============
__global__ __launch_bounds__(256) void conv_tables(const float* __restrict__ tables,
                                                   unsigned* __restrict__ tabp,
                                                   const float* __restrict__ W0,
                                                   const float* __restrict__ W1,
                                                   unsigned short* __restrict__ w0p,
                                                   unsigned short* __restrict__ w1p) {
    const int t = blockIdx.x * 256 + threadIdx.x;
    if (blockIdx.x < 16) {
        const int i = t;
        const int n = i >> 6, k = i & 63;
        w0p[n * 64 + k] = f2bf((k < 35) ? W0[k * 64 + n] : 0.f);
        w1p[n * 64 + k] = f2bf(W1[k * 64 + n]);
    }
    const float4 a = *reinterpret_cast<const float4*>(tables + (size_t)t * 8);
    const float4 b = *reinterpret_cast<const float4*>(tables + (size_t)t * 8 + 4);
    uint4 o;
    o.x = (unsigned)f2bf(a.x) | ((unsigned)f2bf(a.y) << 16);
    o.y = (unsigned)f2bf(a.z) | ((unsigned)f2bf(a.w) << 16);
    o.z = (unsigned)f2bf(b.x) | ((unsigned)f2bf(b.y) << 16);
    o.w = (unsigned)f2bf(b.z) | ((unsigned)f2bf(b.w) << 16);
    *reinterpret_cast<uint4*>(tabp + (size_t)t * 4) = o;
}

// ===================== Pass A1: XCD-pinned gather =====================
// pair = blockIdx & 7 -> XCD (round-robin dispatch). pair p serves levels {p, p+8};
// bf16 footprint 2x2MB = 4MB = one XCD L2. 2048 blocks = 8/CU co-resident.
__global__ __launch_bounds__(256, 8) void nerf_gather_k(
    const float* __restrict__ x, const unsigned* __restrict__ tabp,
    unsigned* __restrict__ feat, int chunkbase, int chunkpts)
{
    const int pair = blockIdx.x & 7;
    const int bip = blockIdx.x >> 3;
    const int nbp = gridDim.x / 8;
    const int l0 = pair, l1 = pair + 8;
    const float r0 = c_res[l0], r1 = c_res[l1];
    const int tid = threadIdx.x;
    const int groups = chunkpts >> 2;
    const int gstride = nbp * 256;
    const unsigned* __restrict__ t0 = tabp + (size_t)l0 * HASHMAP_SIZE;
    const unsigned* __restrict__ t1 = tabp + (size_t)l1 * HASHMAP_SIZE;
    for (int g = bip * 256 + tid; g < groups; g += gstride) {
        const int pl = g * 4;
        const size_t pg = (size_t)chunkbase + pl;
        const float4 xa = *(const float4*)(x + pg * 3 + 0);
        const float4 xb = *(const float4*)(x + pg * 3 + 4);
        const float4 xc = *(const float4*)(x + pg * 3 + 8);
        const unsigned iA0 = hash3(xa.x, xa.y, xa.z, r0), iB0 = hash3(xa.x, xa.y, xa.z, r1);
        const unsigned iA1 = hash3(xa.w, xb.x, xb.y, r0), iB1 = hash3(xa.w, xb.x, xb.y, r1);
        const unsigned iA2 = hash3(xb.z, xb.w, xc.x, r0), iB2 = hash3(xb.z, xb.w, xc.x, r1);
        const unsigned iA3 = hash3(xc.y, xc.z, xc.w, r0), iB3 = hash3(xc.y, xc.z, xc.w, r1);
        u32x4 gA, gB;
        gA.x = t0[iA0]; gA.y = t0[iA1]; gA.z = t0[iA2]; gA.w = t0[iA3];
        gB.x = t1[iB0]; gB.y = t1[iB1]; gB.z = t1[iB2]; gB.w = t1[iB3];
        __builtin_nontemporal_store(gA, (u32x4*)(feat + (size_t)l0 * chunkpts + pl));
        __builtin_nontemporal_store(gB, (u32x4*)(feat + (size_t)l1 * chunkpts + pl));
    }
}

// ===================== Pass B: MLP on MFMA (swapped-operand epilogue) ================
__global__ __launch_bounds__(256, 4) void nerf_mlp_k(
    const unsigned* __restrict__ feat, const float* __restrict__ view_dir,
    const unsigned short* __restrict__ w0p, const unsigned short* __restrict__ w1p,
    const float* __restrict__ b0, const float* __restrict__ b1,
    const float* __restrict__ W2, const float* __restrict__ b2,
    float* __restrict__ out, int chunkbase, int chunkpts)
{
    __shared__ __align__(16) unsigned short acts[256 * 64]; // 32 KB
    char* const actsb = (char*)acts;

    const int tid = threadIdx.x;
    const int gl = blockIdx.x * 256 + tid;
    const size_t gid = (size_t)chunkbase + gl;

    unsigned fw[18];
    #pragma unroll
    for (int l = 0; l < LEVELS; ++l)
        fw[l] = feat[(size_t)l * chunkpts + gl];
    fw[16] = (unsigned)f2bf(view_dir[gid * 3 + 0])
           | ((unsigned)f2bf(view_dir[gid * 3 + 1]) << 16);
    fw[17] = (unsigned)f2bf(view_dir[gid * 3 + 2]);

    {
        const unsigned row = (unsigned)tid;
        #pragma unroll
        for (int c = 0; c < 8; ++c) {
            int4 v;
            if (c < 4)       v = make_int4((int)fw[4*c], (int)fw[4*c+1], (int)fw[4*c+2], (int)fw[4*c+3]);
            else if (c == 4) v = make_int4((int)fw[16], (int)fw[17], 0, 0);
            else             v = make_int4(0, 0, 0, 0);
            *(int4*)(actsb + swz(row, (unsigned)(c * 16))) = v;
        }
    }
    // No barriers: wave w touches only rows [64w, 64w+64).

    const int lane = tid & 63;
    const int lr = lane & 15;
    const int lg = lane >> 4;
    const unsigned Rbase = (unsigned)(tid & ~63);

    // ==== Layers 0 & 1: C' = mfma(W_frag, X_frag) -> lane holds 4 consecutive
    // features of ONE point -> relu + cvt_pk -> single ds_write_b64 per (rt,nt).
    #pragma unroll
    for (int layer = 0; layer < 2; ++layer) {
        const unsigned short* const Wp = layer ? w1p : w0p;
        const float* const bg = layer ? b1 : b0;

        bf16x8 bw[8];
        #pragma unroll
        for (int nt = 0; nt < 4; ++nt)
            #pragma unroll
            for (int ks = 0; ks < 2; ++ks)
                bw[nt * 2 + ks] = *(const bf16x8*)(Wp + (nt * 16 + lr) * 64 + (ks * 32 + lg * 8));

        f32x4 bv[4];
        #pragma unroll
        for (int nt = 0; nt < 4; ++nt)
            bv[nt] = *(const f32x4*)(bg + nt * 16 + lg * 4);

        #pragma unroll
        for (int rt = 0; rt < 4; ++rt) {
            bf16x8 aa[2];
            #pragma unroll
            for (int ks = 0; ks < 2; ++ks) {
                const unsigned row = Rbase + (unsigned)(rt * 16 + lr);
                aa[ks] = *(const bf16x8*)(actsb + swz(row, (unsigned)((ks * 4 + lg) * 16)));
            }
            #pragma unroll
            for (int nt = 0; nt < 4; ++nt) {
                f32x4 c = bv[nt];
                c = __builtin_amdgcn_mfma_f32_16x16x32_bf16(bw[nt * 2 + 0], aa[0], c, 0, 0, 0);
                c = __builtin_amdgcn_mfma_f32_16x16x32_bf16(bw[nt * 2 + 1], aa[1], c, 0, 0, 0);
                // C'[n][point]: this lane: point = rt*16+lr, n = nt*16 + lg*4 + r
                u32x2 pk;
                pk.x = cvt_pk_bf16(fmaxf(c[0], 0.f), fmaxf(c[1], 0.f));
                pk.y = cvt_pk_bf16(fmaxf(c[2], 0.f), fmaxf(c[3], 0.f));
                const unsigned row = Rbase + (unsigned)(rt * 16 + lr);
                *(u32x2*)(actsb + swz(row, (unsigned)(nt * 32 + lg * 8))) = pk;
            }
        }
    }

    // ==== Layer 2 (64->4): swapped mfma -> lanes lg==0 hold all 4 outputs of one
    // point in registers; activations + direct global stores (no LDS bounce).
    {
        bf16x8 bw2[2];
        #pragma unroll
        for (int ks = 0; ks < 2; ++ks) {
            if (lr < 4) bw2[ks] = load_wfrag(W2, 4, lr, ks * 32 + lg * 8, 64);
            else        bw2[ks] = bf16x8{0,0,0,0,0,0,0,0};
        }
        f32x4 c2i = {0.f, 0.f, 0.f, 0.f};
        if (lg == 0) c2i = *(const f32x4*)(b2);
        const size_t gbase = (size_t)chunkbase + (size_t)blockIdx.x * 256 + Rbase;

        #pragma unroll
        for (int rt = 0; rt < 4; ++rt) {
            bf16x8 aa[2];
            #pragma unroll
            for (int ks = 0; ks < 2; ++ks) {
                const unsigned row = Rbase + (unsigned)(rt * 16 + lr);
                aa[ks] = *(const bf16x8*)(actsb + swz(row, (unsigned)((ks * 4 + lg) * 16)));
            }
            f32x4 c = c2i;
            c = __builtin_amdgcn_mfma_f32_16x16x32_bf16(bw2[0], aa[0], c, 0, 0, 0);
            c = __builtin_amdgcn_mfma_f32_16x16x32_bf16(bw2[1], aa[1], c, 0, 0, 0);
            if (lg == 0) {
                const size_t p = gbase + (unsigned)(rt * 16 + lr);
                out[p * 3 + 0] = 1.f / (1.f + __expf(-c[0]));
                out[p * 3 + 1] = 1.f / (1.f + __expf(-c[1]));
                out[p * 3 + 2] = 1.f / (1.f + __expf(-c[2]));
                out[(size_t)N_POINTS * 3 + p] = fmaxf(c[3], 0.f);
            }
        }
    }
}

// ===================== Last-resort fused kernel (tiny ws) ==========================
__global__ __launch_bounds__(256, 4) void nerf_fused(
    const float* __restrict__ x, const float* __restrict__ view_dir,
    const float* __restrict__ tables,
    const float* __restrict__ W0, const float* __restrict__ b0,
    const float* __restrict__ W1, const float* __restrict__ b1,
    const float* __restrict__ W2, const float* __restrict__ b2,
    float* __restrict__ out)
{
    __shared__ __align__(16) unsigned short acts[256 * 64];
    char* const actsb = (char*)acts;
    const int tid = threadIdx.x;
    const int gid = blockIdx.x * 256 + tid;
    const float px = x[gid * 3 + 0], py = x[gid * 3 + 1], pz = x[gid * 3 + 2];

    unsigned idx[LEVELS];
    #pragma unroll
    for (int l = 0; l < LEVELS; ++l) idx[l] = hash3(px, py, pz, c_res[l]);
    float2 f[LEVELS];
    #pragma unroll
    for (int l = 0; l < LEVELS; ++l)
        f[l] = *reinterpret_cast<const float2*>(tables + ((size_t)l * HASHMAP_SIZE + idx[l]) * 2);

    unsigned fw[18];
    #pragma unroll
    for (int l = 0; l < LEVELS; ++l)
        fw[l] = (unsigned)f2bf(f[l].x) | ((unsigned)f2bf(f[l].y) << 16);
    fw[16] = (unsigned)f2bf(view_dir[gid * 3 + 0])
           | ((unsigned)f2bf(view_dir[gid * 3 + 1]) << 16);
    fw[17] = (unsigned)f2bf(view_dir[gid * 3 + 2]);
    {
        const unsigned row = (unsigned)tid;
        #pragma unroll
        for (int c = 0; c < 8; ++c) {
            int4 v;
            if (c < 4)       v = make_int4((int)fw[4*c], (int)fw[4*c+1], (int)fw[4*c+2], (int)fw[4*c+3]);
            else if (c == 4) v = make_int4((int)fw[16], (int)fw[17], 0, 0);
            else             v = make_int4(0, 0, 0, 0);
            *(int4*)(actsb + swz(row, (unsigned)(c * 16))) = v;
        }
    }
    const int lane = tid & 63;
    const int lr = lane & 15;
    const int lg = lane >> 4;
    const unsigned Rbase = (unsigned)(tid & ~63);
    #pragma unroll
    for (int layer = 0; layer < 2; ++layer) {
        const float* const Wg = layer ? W1 : W0;
        const float* const bg = layer ? b1 : b0;
        const int kmax = layer ? 64 : 35;
        bf16x8 bw[8];
        #pragma unroll
        for (int nt = 0; nt < 4; ++nt)
            #pragma unroll
            for (int ks = 0; ks < 2; ++ks)
                bw[nt * 2 + ks] = load_wfrag(Wg, 64, nt * 16 + lr, ks * 32 + lg * 8, kmax);
        #pragma unroll
        for (int rt = 0; rt < 4; ++rt) {
            bf16x8 aa[2];
            #pragma unroll
            for (int ks = 0; ks < 2; ++ks) {
                const unsigned row = Rbase + (unsigned)(rt * 16 + lr);
                aa[ks] = *(const bf16x8*)(actsb + swz(row, (unsigned)((ks * 4 + lg) * 16)));
            }
            #pragma unroll
            for (int nt = 0; nt < 4; ++nt) {
                const float bv = bg[nt * 16 + lr];
                f32x4 c = {bv, bv, bv, bv};
                c = __builtin_amdgcn_mfma_f32_16x16x32_bf16(aa[0], bw[nt * 2 + 0], c, 0, 0, 0);
                c = __builtin_amdgcn_mfma_f32_16x16x32_bf16(aa[1], bw[nt * 2 + 1], c, 0, 0, 0);
                #pragma unroll
                for (int r = 0; r < 4; ++r) {
                    const float v = fmaxf(c[r], 0.f);
                    const unsigned row = Rbase + (unsigned)(rt * 16 + lg * 4 + r);
                    const unsigned col = (unsigned)(nt * 16 + lr);
                    *(unsigned short*)(actsb + swz(row, col * 2)) = f2bf(v);
                }
            }
        }
    }
    {
        float o0 = b2[0], o1 = b2[1], o2 = b2[2], o3 = b2[3];
        const unsigned row = (unsigned)tid;
        #pragma unroll
        for (int c = 0; c < 8; ++c) {
            const bf16x8 v = *(const bf16x8*)(actsb + swz(row, (unsigned)(c * 16)));
            #pragma unroll
            for (int j = 0; j < 8; ++j) {
                const float s = __builtin_bit_cast(float, ((unsigned)(unsigned short)v[j]) << 16);
                const int k = c * 8 + j;
                o0 += s * W2[k * 4 + 0];
                o1 += s * W2[k * 4 + 1];
                o2 += s * W2[k * 4 + 2];
                o3 += s * W2[k * 4 + 3];
            }
        }
        out[(size_t)gid * 3 + 0] = 1.f / (1.f + __expf(-o0));
        out[(size_t)gid * 3 + 1] = 1.f / (1.f + __expf(-o1));
        out[(size_t)gid * 3 + 2] = 1.f / (1.f + __expf(-o2));
        out[(size_t)N_POINTS * 3 + gid] = fmaxf(o3, 0.f);
    }
}

extern "C" void kernel_launch(void* const* d_in, const int* in_sizes, int n_in,
                              void* d_out, int out_size, void* d_ws, size_t ws_size,
                              hipStream_t stream) {
    (void)in_sizes; (void)n_in; (void)out_size;
    const float* x        = (const float*)d_in[0];
    const float* view_dir = (const float*)d_in[1];
    const float* tables   = (const float*)d_in[2];
    const float* W0       = (const float*)d_in[3];
    const float* b0       = (const float*)d_in[4];
    const float* W1       = (const float*)d_in[5];
    const float* b1       = (const float*)d_in[6];
    const float* W2       = (const float*)d_in[7];
    const float* b2       = (const float*)d_in[8];
    float* out = (float*)d_out;

    const size_t TAB_BYTES = (size_t)LEVELS * HASHMAP_SIZE * 4;  // 32 MB packed bf16
    const size_t WP_BYTES  = 16384;                              // 2 x 8 KB packed weights

    int nchunks = 0;
    if      (ws_size >= TAB_BYTES + WP_BYTES + (size_t)N_POINTS * 64) nchunks = 1;
    else if (ws_size >= TAB_BYTES + WP_BYTES + (size_t)N_POINTS * 32) nchunks = 2;
    else if (ws_size >= TAB_BYTES + WP_BYTES + (size_t)N_POINTS * 16) nchunks = 4;

    if (nchunks == 0) {
        nerf_fused<<<N_POINTS / 256, 256, 0, stream>>>(x, view_dir, tables,
                                                       W0, b0, W1, b1, W2, b2, out);
        return;
    }

    unsigned* tabp        = (unsigned*)d_ws;
    unsigned short* w0p   = (unsigned short*)((char*)d_ws + TAB_BYTES);
    unsigned short* w1p   = w0p + 4096;
    unsigned* feat        = (unsigned*)((char*)d_ws + TAB_BYTES + WP_BYTES);
    const int chunkpts = N_POINTS / nchunks;

    conv_tables<<<(LEVELS * HASHMAP_SIZE / 4) / 256, 256, 0, stream>>>(
        tables, tabp, W0, W1, w0p, w1p);

    for (int c = 0; c < nchunks; ++c) {
        const int base = c * chunkpts;
        nerf_gather_k<<<2048, 256, 0, stream>>>(x, tabp, feat, base, chunkpts);
        nerf_mlp_k<<<chunkpts / 256, 256, 0, stream>>>(feat, view_dir, w0p, w1p,
                                                       b0, b1, W2, b2, out,
                                                       base, chunkpts);
    }
}